// Round 6
// baseline (305.292 us; speedup 1.0000x reference)
//
#include <hip/hip_runtime.h>
#include <hip/hip_bf16.h>
#include <math.h>

#define SEQ    2048
#define BATCH  2
#define DM     1024
#define NH     16
#define DH     64
#define BS_ROWS 4096
#define KDIM   1024

typedef __attribute__((ext_vector_type(8))) short short8v;
typedef __attribute__((ext_vector_type(4))) float f32x4;
typedef unsigned short ushort_t;

__device__ __forceinline__ unsigned short f2bf(float f) {
  union { float f; unsigned u; } v; v.f = f;
  unsigned r = (v.u + 0x7FFF + ((v.u >> 16) & 1)) >> 16;
  return (unsigned short)r;
}
__device__ __forceinline__ float bf2f(unsigned short h) {
  union { unsigned u; float f; } v; v.u = ((unsigned)h) << 16;
  return v.f;
}

// async global->LDS, 16B per lane; lds ptr must be wave-uniform base (+lane*16 implied)
__device__ __forceinline__ void gl16(const void* g, void* l) {
  __builtin_amdgcn_global_load_lds(
      (const __attribute__((address_space(1))) unsigned int*)g,
      (__attribute__((address_space(3))) unsigned int*)l,
      16, 0, 0);
}

// ---------------------------------------------------------------------------
// fp32 -> hi/lo bf16 split (8 elems/thread)
// ---------------------------------------------------------------------------
__global__ __launch_bounds__(256)
void split_f32(const float* __restrict__ src, ushort_t* __restrict__ h,
               ushort_t* __restrict__ l, int n8)
{
  const int i = blockIdx.x * 256 + threadIdx.x;
  if (i >= n8) return;
  const float4 v0 = ((const float4*)src)[2 * i];
  const float4 v1 = ((const float4*)src)[2 * i + 1];
  const float vals[8] = {v0.x, v0.y, v0.z, v0.w, v1.x, v1.y, v1.z, v1.w};
  short8v hv, lv;
  #pragma unroll
  for (int e = 0; e < 8; e++) {
    const unsigned short hb = f2bf(vals[e]);
    hv[e] = (short)hb;
    lv[e] = (short)f2bf(vals[e] - bf2f(hb));
  }
  ((short8v*)h)[i] = hv;
  ((short8v*)l)[i] = lv;
}

// ---------------------------------------------------------------------------
// weight transpose + split: Wt[z][hi][n][k] = hi(W[k][n]), Wt[z][lo][n][k] = lo
// ---------------------------------------------------------------------------
__global__ __launch_bounds__(256)
void wtrans(const float* __restrict__ w0, const float* __restrict__ w1,
            const float* __restrict__ w2, const float* __restrict__ w3,
            ushort_t* __restrict__ WT)
{
  __shared__ float tile[64][65];
  const int z = blockIdx.z;
  const float* __restrict__ W = (z == 0) ? w0 : (z == 1) ? w1 : (z == 2) ? w2 : w3;
  ushort_t* __restrict__ Oh = WT + (size_t)z * 2097152;
  ushort_t* __restrict__ Ol = Oh + 1048576;

  const int n0 = blockIdx.x * 64, k0 = blockIdx.y * 64;
  const int r  = threadIdx.x >> 2;
  const int c0 = (threadIdx.x & 3) * 16;

  #pragma unroll
  for (int i = 0; i < 4; i++) {
    const float4 v = *(const float4*)&W[(size_t)(k0 + r) * KDIM + n0 + c0 + 4 * i];
    tile[r][c0 + 4 * i + 0] = v.x; tile[r][c0 + 4 * i + 1] = v.y;
    tile[r][c0 + 4 * i + 2] = v.z; tile[r][c0 + 4 * i + 3] = v.w;
  }
  __syncthreads();

  #pragma unroll
  for (int c = 0; c < 2; c++) {
    short8v hv, lv;
    #pragma unroll
    for (int e = 0; e < 8; e++) {
      const float x = tile[c0 + c * 8 + e][r];
      const unsigned short hb = f2bf(x);
      hv[e] = (short)hb;
      lv[e] = (short)f2bf(x - bf2f(hb));
    }
    const size_t off = (size_t)(n0 + r) * KDIM + k0 + c0 + c * 8;
    *(short8v*)&Oh[off] = hv;
    *(short8v*)&Ol[off] = lv;
  }
}

// ---------------------------------------------------------------------------
// Split-bf16 MFMA GEMM (unchanged from round 5 — verified, ~880 TF).
// ---------------------------------------------------------------------------
#define MM3(Ah_, Al_, Bh_, Bl_, C_)                                          \
  C_ = __builtin_amdgcn_mfma_f32_16x16x32_bf16(Ah_, Bh_, C_, 0, 0, 0);       \
  C_ = __builtin_amdgcn_mfma_f32_16x16x32_bf16(Ah_, Bl_, C_, 0, 0, 0);       \
  C_ = __builtin_amdgcn_mfma_f32_16x16x32_bf16(Al_, Bh_, C_, 0, 0, 0);

__global__ __launch_bounds__(256, 2)
void mfma_gemm(const ushort_t* __restrict__ Ah, const ushort_t* __restrict__ Al,
               const ushort_t* __restrict__ WT, int zbase,
               ushort_t* __restrict__ Qh, ushort_t* __restrict__ Ql,
               ushort_t* __restrict__ Kh, ushort_t* __restrict__ Kl,
               ushort_t* __restrict__ Vt, float* __restrict__ Cf)
{
  const int mode = zbase + blockIdx.z;
  const ushort_t* __restrict__ Bh = WT + (size_t)mode * 2097152;
  const ushort_t* __restrict__ Bl = Bh + 1048576;

  __shared__ ushort_t Ash[128][32];
  __shared__ ushort_t Asl[128][32];
  __shared__ ushort_t Bsh[128][32];
  __shared__ ushort_t Bsl[128][32];

  const int t = threadIdx.x;
  const int lane = t & 63, w = t >> 6;
  const int l4 = lane & 15, lh = lane >> 4;
  const int wm = w >> 1, wn = w & 1;
  const int row0 = blockIdx.y * 128, col0 = blockIdx.x * 128;

  const int srow = t >> 2;           // 0..63
  const int scol = (t & 3) * 8;      // 0,8,16,24

  f32x4 c00 = {0,0,0,0}, c01 = {0,0,0,0}, c02 = {0,0,0,0}, c03 = {0,0,0,0};
  f32x4 c10 = {0,0,0,0}, c11 = {0,0,0,0}, c12 = {0,0,0,0}, c13 = {0,0,0,0};
  f32x4 c20 = {0,0,0,0}, c21 = {0,0,0,0}, c22 = {0,0,0,0}, c23 = {0,0,0,0};
  f32x4 c30 = {0,0,0,0}, c31 = {0,0,0,0}, c32 = {0,0,0,0}, c33 = {0,0,0,0};

  const int rA = wm * 64 + l4;
  const int rB = wn * 64 + l4;
  const int cF = lh * 8;

  for (int k0 = 0; k0 < KDIM; k0 += 32) {
    #pragma unroll
    for (int r = 0; r < 2; r++) {
      const int row = srow + r * 64;
      const size_t gA = (size_t)(row0 + row) * KDIM + k0 + scol;
      const size_t gB = (size_t)(col0 + row) * KDIM + k0 + scol;
      const int lo = w * 1024 + r * 4096;
      gl16(Ah + gA, (char*)Ash + lo);
      gl16(Al + gA, (char*)Asl + lo);
      gl16(Bh + gB, (char*)Bsh + lo);
      gl16(Bl + gB, (char*)Bsl + lo);
    }
    __syncthreads();

    const short8v ah0 = *(const short8v*)&Ash[rA +  0][cF];
    const short8v ah1 = *(const short8v*)&Ash[rA + 16][cF];
    const short8v ah2 = *(const short8v*)&Ash[rA + 32][cF];
    const short8v ah3 = *(const short8v*)&Ash[rA + 48][cF];
    const short8v al0 = *(const short8v*)&Asl[rA +  0][cF];
    const short8v al1 = *(const short8v*)&Asl[rA + 16][cF];
    const short8v al2 = *(const short8v*)&Asl[rA + 32][cF];
    const short8v al3 = *(const short8v*)&Asl[rA + 48][cF];
    const short8v bh0 = *(const short8v*)&Bsh[rB +  0][cF];
    const short8v bh1 = *(const short8v*)&Bsh[rB + 16][cF];
    const short8v bh2 = *(const short8v*)&Bsh[rB + 32][cF];
    const short8v bh3 = *(const short8v*)&Bsh[rB + 48][cF];
    const short8v bl0 = *(const short8v*)&Bsl[rB +  0][cF];
    const short8v bl1 = *(const short8v*)&Bsl[rB + 16][cF];
    const short8v bl2 = *(const short8v*)&Bsl[rB + 32][cF];
    const short8v bl3 = *(const short8v*)&Bsl[rB + 48][cF];

    MM3(ah0, al0, bh0, bl0, c00)  MM3(ah0, al0, bh1, bl1, c01)
    MM3(ah0, al0, bh2, bl2, c02)  MM3(ah0, al0, bh3, bl3, c03)
    MM3(ah1, al1, bh0, bl0, c10)  MM3(ah1, al1, bh1, bl1, c11)
    MM3(ah1, al1, bh2, bl2, c12)  MM3(ah1, al1, bh3, bl3, c13)
    MM3(ah2, al2, bh0, bl0, c20)  MM3(ah2, al2, bh1, bl1, c21)
    MM3(ah2, al2, bh2, bl2, c22)  MM3(ah2, al2, bh3, bl3, c23)
    MM3(ah3, al3, bh0, bl0, c30)  MM3(ah3, al3, bh1, bl1, c31)
    MM3(ah3, al3, bh2, bl2, c32)  MM3(ah3, al3, bh3, bl3, c33)
    __syncthreads();
  }

  f32x4 acc[4][4];
  acc[0][0]=c00; acc[0][1]=c01; acc[0][2]=c02; acc[0][3]=c03;
  acc[1][0]=c10; acc[1][1]=c11; acc[1][2]=c12; acc[1][3]=c13;
  acc[2][0]=c20; acc[2][1]=c21; acc[2][2]=c22; acc[2][3]=c23;
  acc[3][0]=c30; acc[3][1]=c31; acc[3][2]=c32; acc[3][3]=c33;

  if (mode <= 1) {
    const float scale = (mode == 0) ? 0.03125f : 1.0f;
    ushort_t* __restrict__ Hp = (mode == 0) ? Qh : Kh;
    ushort_t* __restrict__ Lp = (mode == 0) ? Ql : Kl;
    #pragma unroll
    for (int mf = 0; mf < 4; mf++)
      #pragma unroll
      for (int nf = 0; nf < 4; nf++) {
        const int col = col0 + wn * 64 + nf * 16 + l4;
        const int p = (col & (DH - 1)) >> 1;
        const float fr = exp2f((float)p * -0.41524101186092030f);
        const float sgn = (col & 1) ? 1.0f : -1.0f;
        #pragma unroll
        for (int j = 0; j < 4; j++) {
          const int grow = row0 + wm * 64 + mf * 16 + lh * 4 + j;
          const float s = (float)(grow & (SEQ - 1));
          float sn, cs;
          sincosf(s * fr, &sn, &cs);
          const float val = acc[mf][nf][j];
          const float par = __shfl_xor(val, 1);
          const float out = val * cs + par * (sgn * sn);
          const float xsc = out * scale;
          const unsigned short hb = f2bf(xsc);
          Hp[(size_t)grow * DM + col] = hb;
          Lp[(size_t)grow * DM + col] = f2bf(xsc - bf2f(hb));
        }
      }
  } else if (mode == 2) {
    #pragma unroll
    for (int mf = 0; mf < 4; mf++)
      #pragma unroll
      for (int nf = 0; nf < 4; nf++) {
        const int col = col0 + wn * 64 + nf * 16 + l4;
        const int hh = col >> 6, dd = col & (DH - 1);
        #pragma unroll
        for (int j = 0; j < 4; j++) {
          const int grow = row0 + wm * 64 + mf * 16 + lh * 4 + j;
          const int b = grow >> 11, ss = grow & (SEQ - 1);
          Vt[((size_t)((b * NH + hh) * DH + dd)) * SEQ + ss] = f2bf(acc[mf][nf][j]);
        }
      }
  } else {
    #pragma unroll
    for (int mf = 0; mf < 4; mf++)
      #pragma unroll
      for (int nf = 0; nf < 4; nf++) {
        const int col = col0 + wn * 64 + nf * 16 + l4;
        #pragma unroll
        for (int j = 0; j < 4; j++) {
          const int grow = row0 + wm * 64 + mf * 16 + lh * 4 + j;
          Cf[(size_t)grow * DM + col] = acc[mf][nf][j];
        }
      }
  }
}

// ---------------------------------------------------------------------------
// MFMA flash attention, round 6: double-buffered K/V (reg-staged prefetch,
// ONE barrier per tile), XOR-swizzled K LDS (8-way -> 2-way), hi/lo split
// epilogue (writes AAh/AAl bf16 directly).
// ---------------------------------------------------------------------------
__global__ __launch_bounds__(256)
void attn_mfma(const ushort_t* __restrict__ Qh, const ushort_t* __restrict__ Ql,
               const ushort_t* __restrict__ Kh, const ushort_t* __restrict__ Kl,
               const ushort_t* __restrict__ Vt,
               ushort_t* __restrict__ AAh, ushort_t* __restrict__ AAl)
{
  __shared__ __align__(16) ushort_t Khl[2][2][2][64][32]; // [buf][hi/lo][db][kr][d] 32KB
  __shared__ __align__(16) ushort_t Vtl[2][64][72];       // [buf][d][k]            18.4KB
  __shared__ __align__(16) ushort_t Pl[4][16][72];        // per-wave P              9.2KB

  const int t = threadIdx.x;
  const int lane = t & 63, w = t >> 6;
  const int l4 = lane & 15, lh = lane >> 4;
  const int qblk = blockIdx.x, bh = blockIdx.y;
  const int bI = bh >> 4, h = bh & 15;
  const int q0w = qblk * 64 + w * 16;

  // staging indices; swizzle: chunk' = chunk ^ ((row>>1)&3)  (2-way, free)
  const int kr = t >> 2, kc = t & 3;
  const int ckw = (kc ^ ((kr >> 1) & 3)) * 8;      // write chunk (ushort idx)
  const int csr = (lh ^ ((l4 >> 1) & 3)) * 8;      // read chunk — krow>>1&3 == l4>>1&3

  short8v aq[2][2];
  {
    const size_t qoff = (size_t)((bI * SEQ) + (q0w + l4)) * DM + h * DH;
    #pragma unroll
    for (int db = 0; db < 2; db++) {
      aq[0][db] = *(const short8v*)&Qh[qoff + db * 32 + lh * 8];
      aq[1][db] = *(const short8v*)&Ql[qoff + db * 32 + lh * 8];
    }
  }

  f32x4 o[4];
  float m[4], ls[4];
  #pragma unroll
  for (int j = 0; j < 4; j++) {
    o[j] = (f32x4){0.f, 0.f, 0.f, 0.f};
    m[j] = -1e30f; ls[j] = 0.f;
  }

  const ushort_t* __restrict__ Vg = Vt + (size_t)bh * DH * SEQ;
  const size_t kbase = (size_t)(bI * SEQ + kr) * DM + h * DH + kc * 8;
  const int nt = qblk + 1;

  short8v rkh0, rkh1, rkl0, rkl1, rv0, rv1;

#define LOADR(kt_) {                                                         \
    const size_t ko = kbase + (size_t)(kt_) * 64 * DM;                       \
    rkh0 = *(const short8v*)&Kh[ko];                                         \
    rkh1 = *(const short8v*)&Kh[ko + 32];                                    \
    rkl0 = *(const short8v*)&Kl[ko];                                         \
    rkl1 = *(const short8v*)&Kl[ko + 32];                                    \
    const size_t vo = (size_t)kr * SEQ + (kt_) * 64 + kc * 8;                \
    rv0 = *(const short8v*)&Vg[vo];                                          \
    rv1 = *(const short8v*)&Vg[vo + 32]; }

#define WRITES(bf_) {                                                        \
    *(short8v*)&Khl[bf_][0][0][kr][ckw] = rkh0;                              \
    *(short8v*)&Khl[bf_][0][1][kr][ckw] = rkh1;                              \
    *(short8v*)&Khl[bf_][1][0][kr][ckw] = rkl0;                              \
    *(short8v*)&Khl[bf_][1][1][kr][ckw] = rkl1;                              \
    *(short8v*)&Vtl[bf_][kr][kc * 8]      = rv0;                             \
    *(short8v*)&Vtl[bf_][kr][kc * 8 + 32] = rv1; }

  LOADR(0); WRITES(0);
  __syncthreads();
  int cur = 0;

  for (int kt = 0; kt < nt; kt++) {
    const bool pf = (kt + 1 < nt);
    if (pf) LOADR(kt + 1);

    // ---- S = Q K^T  (split bf16: hi*hi + hi*lo + lo*hi)
    f32x4 s[4];
    #pragma unroll
    for (int n = 0; n < 4; n++) s[n] = (f32x4){0.f, 0.f, 0.f, 0.f};
    #pragma unroll
    for (int n = 0; n < 4; n++) {
      const int krow = n * 16 + l4;
      #pragma unroll
      for (int db = 0; db < 2; db++) {
        short8v bhv = *(const short8v*)&Khl[cur][0][db][krow][csr];
        short8v blv = *(const short8v*)&Khl[cur][1][db][krow][csr];
        s[n] = __builtin_amdgcn_mfma_f32_16x16x32_bf16(aq[0][db], bhv, s[n], 0, 0, 0);
        s[n] = __builtin_amdgcn_mfma_f32_16x16x32_bf16(aq[0][db], blv, s[n], 0, 0, 0);
        s[n] = __builtin_amdgcn_mfma_f32_16x16x32_bf16(aq[1][db], bhv, s[n], 0, 0, 0);
      }
    }

    // ---- causal mask + online softmax
    const int kb = kt * 64;
    #pragma unroll
    for (int j = 0; j < 4; j++) {
      const int qg = q0w + lh * 4 + j;
      #pragma unroll
      for (int n = 0; n < 4; n++)
        if (kb + n * 16 + l4 > qg) s[n][j] = -1e30f;

      float v = fmaxf(fmaxf(s[0][j], s[1][j]), fmaxf(s[2][j], s[3][j]));
      #pragma unroll
      for (int off = 1; off < 16; off <<= 1) v = fmaxf(v, __shfl_xor(v, off));
      const float nm = fmaxf(m[j], v);
      const float corr = __expf(m[j] - nm);
      m[j] = nm;
      float rs = 0.f;
      #pragma unroll
      for (int n = 0; n < 4; n++) {
        const float p = __expf(s[n][j] - nm);
        s[n][j] = p;
        rs += p;
      }
      #pragma unroll
      for (int off = 1; off < 16; off <<= 1) rs += __shfl_xor(rs, off);
      ls[j] = ls[j] * corr + rs;
      #pragma unroll
      for (int df = 0; df < 4; df++) o[df][j] *= corr;
    }

    // ---- P -> LDS (per-wave buffer; same-wave write->read, no barrier)
    #pragma unroll
    for (int n = 0; n < 4; n++)
      #pragma unroll
      for (int j = 0; j < 4; j++)
        Pl[w][lh * 4 + j][n * 16 + l4] = f2bf(s[n][j]);

    // ---- O += P V
    #pragma unroll
    for (int kb2 = 0; kb2 < 2; kb2++) {
      short8v ap = *(const short8v*)&Pl[w][l4][kb2 * 32 + lh * 8];
      #pragma unroll
      for (int df = 0; df < 4; df++) {
        short8v bv = *(const short8v*)&Vtl[cur][df * 16 + l4][kb2 * 32 + lh * 8];
        o[df] = __builtin_amdgcn_mfma_f32_16x16x32_bf16(ap, bv, o[df], 0, 0, 0);
      }
    }

    // ---- publish next tile into buf^1 (no reader conflict), one barrier
    if (pf) WRITES(cur ^ 1);
    __syncthreads();
    cur ^= 1;
  }

  // ---- epilogue: normalize + hi/lo bf16 split (replaces split_f32 pass)
  #pragma unroll
  for (int j = 0; j < 4; j++) {
    const float inv = 1.0f / ls[j];
    const size_t row = (size_t)(bI * SEQ + q0w + lh * 4 + j);
    #pragma unroll
    for (int df = 0; df < 4; df++) {
      const int col = h * DH + df * 16 + l4;
      const float x = o[df][j] * inv;
      const unsigned short hb = f2bf(x);
      AAh[row * DM + col] = hb;
      AAl[row * DM + col] = f2bf(x - bf2f(hb));
    }
  }
#undef LOADR
#undef WRITES
}

// ---------------------------------------------------------------------------
// ws layout (56 MB):
//   0MB: Xh(8) Xl(8)      -> after QKV consumed: AAh(8) AAl(8) from attn
//  16MB: Kh(8) Kl(8)
//  32MB: Vt(8)
//  40MB: WT 4x(hi 2MB + lo 2MB) = 16
// d_out: Qh(8) Ql(8) scratch, then final fp32 out (16).
// ---------------------------------------------------------------------------
extern "C" void kernel_launch(void* const* d_in, const int* in_sizes, int n_in,
                              void* d_out, int out_size, void* d_ws, size_t ws_size,
                              hipStream_t stream) {
  const float* x  = (const float*)d_in[0];
  const float* qw = (const float*)d_in[1];
  const float* kw = (const float*)d_in[2];
  const float* vw = (const float*)d_in[3];
  const float* ow = (const float*)d_in[4];

  char* ws = (char*)d_ws;
  ushort_t* Xh  = (ushort_t*)ws;
  ushort_t* Xl  = Xh + 4194304;
  ushort_t* AAh = Xh;                      // Xh/Xl dead after QKV gemm
  ushort_t* AAl = Xl;
  ushort_t* Kh  = (ushort_t*)(ws + (16u << 20));
  ushort_t* Kl  = Kh + 4194304;
  ushort_t* Vt  = (ushort_t*)(ws + (32u << 20));
  ushort_t* WT  = (ushort_t*)(ws + (40u << 20));
  ushort_t* Qh  = (ushort_t*)d_out;
  ushort_t* Ql  = Qh + 4194304;
  float*    out = (float*)d_out;

  dim3 blk(256);
  split_f32<<<dim3(2048), blk, 0, stream>>>(x, Xh, Xl, 524288);
  wtrans<<<dim3(16, 16, 4), blk, 0, stream>>>(qw, kw, vw, ow, WT);
  mfma_gemm<<<dim3(8, 32, 3), blk, 0, stream>>>(
      Xh, Xl, WT, 0, Qh, Ql, Kh, Kl, Vt, nullptr);
  attn_mfma<<<dim3(SEQ / 64, BATCH * NH), blk, 0, stream>>>(
      Qh, Ql, Kh, Kl, Vt, AAh, AAl);
  mfma_gemm<<<dim3(8, 32, 1), blk, 0, stream>>>(
      AAh, AAl, WT, 3, nullptr, nullptr, nullptr, nullptr, nullptr, out);
}

// Round 7
// 245.358 us; speedup vs baseline: 1.2443x; 1.2443x over previous
//
#include <hip/hip_runtime.h>
#include <hip/hip_bf16.h>
#include <math.h>

#define SEQ    2048
#define BATCH  2
#define DM     1024
#define NH     16
#define DH     64
#define BS_ROWS 4096
#define KDIM   1024

typedef __attribute__((ext_vector_type(8))) short short8v;
typedef __attribute__((ext_vector_type(4))) float f32x4;
typedef unsigned short ushort_t;

__device__ __forceinline__ unsigned short f2bf(float f) {
  union { float f; unsigned u; } v; v.f = f;
  unsigned r = (v.u + 0x7FFF + ((v.u >> 16) & 1)) >> 16;
  return (unsigned short)r;
}
__device__ __forceinline__ float bf2f(unsigned short h) {
  union { unsigned u; float f; } v; v.u = ((unsigned)h) << 16;
  return v.f;
}

// async global->LDS, 16B per lane; lds ptr must be wave-uniform base (+lane*16 implied)
__device__ __forceinline__ void gl16(const void* g, void* l) {
  __builtin_amdgcn_global_load_lds(
      (const __attribute__((address_space(1))) unsigned int*)g,
      (__attribute__((address_space(3))) unsigned int*)l,
      16, 0, 0);
}

// ---------------------------------------------------------------------------
// fp32 -> hi/lo bf16 split (8 elems/thread)
// ---------------------------------------------------------------------------
__global__ __launch_bounds__(256)
void split_f32(const float* __restrict__ src, ushort_t* __restrict__ h,
               ushort_t* __restrict__ l, int n8)
{
  const int i = blockIdx.x * 256 + threadIdx.x;
  if (i >= n8) return;
  const float4 v0 = ((const float4*)src)[2 * i];
  const float4 v1 = ((const float4*)src)[2 * i + 1];
  const float vals[8] = {v0.x, v0.y, v0.z, v0.w, v1.x, v1.y, v1.z, v1.w};
  short8v hv, lv;
  #pragma unroll
  for (int e = 0; e < 8; e++) {
    const unsigned short hb = f2bf(vals[e]);
    hv[e] = (short)hb;
    lv[e] = (short)f2bf(vals[e] - bf2f(hb));
  }
  ((short8v*)h)[i] = hv;
  ((short8v*)l)[i] = lv;
}

// ---------------------------------------------------------------------------
// weight transpose + split: Wt[z][hi][n][k] = hi(W[k][n]), Wt[z][lo][n][k] = lo
// ---------------------------------------------------------------------------
__global__ __launch_bounds__(256)
void wtrans(const float* __restrict__ w0, const float* __restrict__ w1,
            const float* __restrict__ w2, const float* __restrict__ w3,
            ushort_t* __restrict__ WT)
{
  __shared__ float tile[64][65];
  const int z = blockIdx.z;
  const float* __restrict__ W = (z == 0) ? w0 : (z == 1) ? w1 : (z == 2) ? w2 : w3;
  ushort_t* __restrict__ Oh = WT + (size_t)z * 2097152;
  ushort_t* __restrict__ Ol = Oh + 1048576;

  const int n0 = blockIdx.x * 64, k0 = blockIdx.y * 64;
  const int r  = threadIdx.x >> 2;
  const int c0 = (threadIdx.x & 3) * 16;

  #pragma unroll
  for (int i = 0; i < 4; i++) {
    const float4 v = *(const float4*)&W[(size_t)(k0 + r) * KDIM + n0 + c0 + 4 * i];
    tile[r][c0 + 4 * i + 0] = v.x; tile[r][c0 + 4 * i + 1] = v.y;
    tile[r][c0 + 4 * i + 2] = v.z; tile[r][c0 + 4 * i + 3] = v.w;
  }
  __syncthreads();

  #pragma unroll
  for (int c = 0; c < 2; c++) {
    short8v hv, lv;
    #pragma unroll
    for (int e = 0; e < 8; e++) {
      const float x = tile[c0 + c * 8 + e][r];
      const unsigned short hb = f2bf(x);
      hv[e] = (short)hb;
      lv[e] = (short)f2bf(x - bf2f(hb));
    }
    const size_t off = (size_t)(n0 + r) * KDIM + k0 + c0 + c * 8;
    *(short8v*)&Oh[off] = hv;
    *(short8v*)&Ol[off] = lv;
  }
}

// ---------------------------------------------------------------------------
// Split-bf16 MFMA GEMM (unchanged — verified, ~880 TF).
// ---------------------------------------------------------------------------
#define MM3(Ah_, Al_, Bh_, Bl_, C_)                                          \
  C_ = __builtin_amdgcn_mfma_f32_16x16x32_bf16(Ah_, Bh_, C_, 0, 0, 0);       \
  C_ = __builtin_amdgcn_mfma_f32_16x16x32_bf16(Ah_, Bl_, C_, 0, 0, 0);       \
  C_ = __builtin_amdgcn_mfma_f32_16x16x32_bf16(Al_, Bh_, C_, 0, 0, 0);

__global__ __launch_bounds__(256, 2)
void mfma_gemm(const ushort_t* __restrict__ Ah, const ushort_t* __restrict__ Al,
               const ushort_t* __restrict__ WT, int zbase,
               ushort_t* __restrict__ Qh, ushort_t* __restrict__ Ql,
               ushort_t* __restrict__ Kh, ushort_t* __restrict__ Kl,
               ushort_t* __restrict__ Vt, float* __restrict__ Cf)
{
  const int mode = zbase + blockIdx.z;
  const ushort_t* __restrict__ Bh = WT + (size_t)mode * 2097152;
  const ushort_t* __restrict__ Bl = Bh + 1048576;

  __shared__ ushort_t Ash[128][32];
  __shared__ ushort_t Asl[128][32];
  __shared__ ushort_t Bsh[128][32];
  __shared__ ushort_t Bsl[128][32];

  const int t = threadIdx.x;
  const int lane = t & 63, w = t >> 6;
  const int l4 = lane & 15, lh = lane >> 4;
  const int wm = w >> 1, wn = w & 1;
  const int row0 = blockIdx.y * 128, col0 = blockIdx.x * 128;

  const int srow = t >> 2;
  const int scol = (t & 3) * 8;

  f32x4 c00 = {0,0,0,0}, c01 = {0,0,0,0}, c02 = {0,0,0,0}, c03 = {0,0,0,0};
  f32x4 c10 = {0,0,0,0}, c11 = {0,0,0,0}, c12 = {0,0,0,0}, c13 = {0,0,0,0};
  f32x4 c20 = {0,0,0,0}, c21 = {0,0,0,0}, c22 = {0,0,0,0}, c23 = {0,0,0,0};
  f32x4 c30 = {0,0,0,0}, c31 = {0,0,0,0}, c32 = {0,0,0,0}, c33 = {0,0,0,0};

  const int rA = wm * 64 + l4;
  const int rB = wn * 64 + l4;
  const int cF = lh * 8;

  for (int k0 = 0; k0 < KDIM; k0 += 32) {
    #pragma unroll
    for (int r = 0; r < 2; r++) {
      const int row = srow + r * 64;
      const size_t gA = (size_t)(row0 + row) * KDIM + k0 + scol;
      const size_t gB = (size_t)(col0 + row) * KDIM + k0 + scol;
      const int lo = w * 1024 + r * 4096;
      gl16(Ah + gA, (char*)Ash + lo);
      gl16(Al + gA, (char*)Asl + lo);
      gl16(Bh + gB, (char*)Bsh + lo);
      gl16(Bl + gB, (char*)Bsl + lo);
    }
    __syncthreads();

    const short8v ah0 = *(const short8v*)&Ash[rA +  0][cF];
    const short8v ah1 = *(const short8v*)&Ash[rA + 16][cF];
    const short8v ah2 = *(const short8v*)&Ash[rA + 32][cF];
    const short8v ah3 = *(const short8v*)&Ash[rA + 48][cF];
    const short8v al0 = *(const short8v*)&Asl[rA +  0][cF];
    const short8v al1 = *(const short8v*)&Asl[rA + 16][cF];
    const short8v al2 = *(const short8v*)&Asl[rA + 32][cF];
    const short8v al3 = *(const short8v*)&Asl[rA + 48][cF];
    const short8v bh0 = *(const short8v*)&Bsh[rB +  0][cF];
    const short8v bh1 = *(const short8v*)&Bsh[rB + 16][cF];
    const short8v bh2 = *(const short8v*)&Bsh[rB + 32][cF];
    const short8v bh3 = *(const short8v*)&Bsh[rB + 48][cF];
    const short8v bl0 = *(const short8v*)&Bsl[rB +  0][cF];
    const short8v bl1 = *(const short8v*)&Bsl[rB + 16][cF];
    const short8v bl2 = *(const short8v*)&Bsl[rB + 32][cF];
    const short8v bl3 = *(const short8v*)&Bsl[rB + 48][cF];

    MM3(ah0, al0, bh0, bl0, c00)  MM3(ah0, al0, bh1, bl1, c01)
    MM3(ah0, al0, bh2, bl2, c02)  MM3(ah0, al0, bh3, bl3, c03)
    MM3(ah1, al1, bh0, bl0, c10)  MM3(ah1, al1, bh1, bl1, c11)
    MM3(ah1, al1, bh2, bl2, c12)  MM3(ah1, al1, bh3, bl3, c13)
    MM3(ah2, al2, bh0, bl0, c20)  MM3(ah2, al2, bh1, bl1, c21)
    MM3(ah2, al2, bh2, bl2, c22)  MM3(ah2, al2, bh3, bl3, c23)
    MM3(ah3, al3, bh0, bl0, c30)  MM3(ah3, al3, bh1, bl1, c31)
    MM3(ah3, al3, bh2, bl2, c32)  MM3(ah3, al3, bh3, bl3, c33)
    __syncthreads();
  }

  f32x4 acc[4][4];
  acc[0][0]=c00; acc[0][1]=c01; acc[0][2]=c02; acc[0][3]=c03;
  acc[1][0]=c10; acc[1][1]=c11; acc[1][2]=c12; acc[1][3]=c13;
  acc[2][0]=c20; acc[2][1]=c21; acc[2][2]=c22; acc[2][3]=c23;
  acc[3][0]=c30; acc[3][1]=c31; acc[3][2]=c32; acc[3][3]=c33;

  if (mode <= 1) {
    const float scale = (mode == 0) ? 0.03125f : 1.0f;
    ushort_t* __restrict__ Hp = (mode == 0) ? Qh : Kh;
    ushort_t* __restrict__ Lp = (mode == 0) ? Ql : Kl;
    #pragma unroll
    for (int mf = 0; mf < 4; mf++)
      #pragma unroll
      for (int nf = 0; nf < 4; nf++) {
        const int col = col0 + wn * 64 + nf * 16 + l4;
        const int p = (col & (DH - 1)) >> 1;
        const float fr = exp2f((float)p * -0.41524101186092030f);
        const float sgn = (col & 1) ? 1.0f : -1.0f;
        #pragma unroll
        for (int j = 0; j < 4; j++) {
          const int grow = row0 + wm * 64 + mf * 16 + lh * 4 + j;
          const float s = (float)(grow & (SEQ - 1));
          float sn, cs;
          sincosf(s * fr, &sn, &cs);
          const float val = acc[mf][nf][j];
          const float par = __shfl_xor(val, 1);
          const float out = val * cs + par * (sgn * sn);
          const float xsc = out * scale;
          const unsigned short hb = f2bf(xsc);
          Hp[(size_t)grow * DM + col] = hb;
          Lp[(size_t)grow * DM + col] = f2bf(xsc - bf2f(hb));
        }
      }
  } else if (mode == 2) {
    #pragma unroll
    for (int mf = 0; mf < 4; mf++)
      #pragma unroll
      for (int nf = 0; nf < 4; nf++) {
        const int col = col0 + wn * 64 + nf * 16 + l4;
        const int hh = col >> 6, dd = col & (DH - 1);
        #pragma unroll
        for (int j = 0; j < 4; j++) {
          const int grow = row0 + wm * 64 + mf * 16 + lh * 4 + j;
          const int b = grow >> 11, ss = grow & (SEQ - 1);
          Vt[((size_t)((b * NH + hh) * DH + dd)) * SEQ + ss] = f2bf(acc[mf][nf][j]);
        }
      }
  } else {
    #pragma unroll
    for (int mf = 0; mf < 4; mf++)
      #pragma unroll
      for (int nf = 0; nf < 4; nf++) {
        const int col = col0 + wn * 64 + nf * 16 + l4;
        #pragma unroll
        for (int j = 0; j < 4; j++) {
          const int grow = row0 + wm * 64 + mf * 16 + lh * 4 + j;
          Cf[(size_t)grow * DM + col] = acc[mf][nf][j];
        }
      }
  }
}

// ---------------------------------------------------------------------------
// MFMA flash attention, round 7: SWAPPED QK^T (S^T = K Q^T) so each lane owns
// one q-row -> lane-local softmax, lane-uniform rescale; O accumulated as O^T.
// Single-buffered K/V (34.8KB LDS -> 4 blocks/CU) with early-issued register
// prefetch (loads overlap compute, write-after-barrier). K LDS XOR-swizzled.
// ---------------------------------------------------------------------------
__global__ __launch_bounds__(256, 4)
void attn_mfma(const ushort_t* __restrict__ Qh, const ushort_t* __restrict__ Ql,
               const ushort_t* __restrict__ Kh, const ushort_t* __restrict__ Kl,
               const ushort_t* __restrict__ Vt,
               ushort_t* __restrict__ AAh, ushort_t* __restrict__ AAl)
{
  __shared__ __align__(16) ushort_t Khl[2][2][64][32]; // [hi/lo][db][row][d] 16KB
  __shared__ __align__(16) ushort_t Vtl[64][72];       // [d][k]             9.2KB
  __shared__ __align__(16) ushort_t Pl[4][16][72];     // [wave][q][k]       9.2KB

  const int t = threadIdx.x;
  const int lane = t & 63, wv = t >> 6;
  const int l4 = lane & 15, lh = lane >> 4;
  const int qblk = blockIdx.x, bh = blockIdx.y;
  const int bI = bh >> 4, h = bh & 15;
  const int q0w = qblk * 64 + wv * 16;
  const int qrow = q0w + l4;                 // this lane's q row (global s-index)

  // staging indices; K swizzle: chunk' = chunk ^ ((row>>1)&3)
  const int kr = t >> 2, kc = t & 3;
  const int ckw = (kc ^ ((kr >> 1) & 3)) * 8;      // write chunk
  const int csr = (lh ^ ((l4 >> 1) & 3)) * 8;      // read chunk (rows n*16+l4)

  // Q fragments (B-operand): lane l4 = q col, (lh,e) = d
  short8v aqh0, aqh1, aql0, aql1;
  {
    const size_t qoff = (size_t)((bI * SEQ) + qrow) * DM + h * DH;
    aqh0 = *(const short8v*)&Qh[qoff + lh * 8];
    aqh1 = *(const short8v*)&Qh[qoff + 32 + lh * 8];
    aql0 = *(const short8v*)&Ql[qoff + lh * 8];
    aql1 = *(const short8v*)&Ql[qoff + 32 + lh * 8];
  }

  f32x4 o0 = {0,0,0,0}, o1 = {0,0,0,0}, o2 = {0,0,0,0}, o3 = {0,0,0,0};
  float mrun = -1e30f, lsum = 0.f;

  const ushort_t* __restrict__ Vg = Vt + (size_t)bh * DH * SEQ;
  const size_t kgbase = (size_t)(bI * SEQ + kr) * DM + h * DH + kc * 8;
  const int nt = qblk + 1;

  short8v rkh0, rkh1, rkl0, rkl1, rv0, rv1;

#define LOADR(kt_) {                                                         \
    const size_t ko = kgbase + (size_t)(kt_) * 64 * DM;                      \
    rkh0 = *(const short8v*)&Kh[ko];                                         \
    rkh1 = *(const short8v*)&Kh[ko + 32];                                    \
    rkl0 = *(const short8v*)&Kl[ko];                                         \
    rkl1 = *(const short8v*)&Kl[ko + 32];                                    \
    const size_t vo = (size_t)kr * SEQ + (kt_) * 64 + kc * 8;                \
    rv0 = *(const short8v*)&Vg[vo];                                          \
    rv1 = *(const short8v*)&Vg[vo + 32]; }

#define WRITES() {                                                           \
    *(short8v*)&Khl[0][0][kr][ckw] = rkh0;                                   \
    *(short8v*)&Khl[0][1][kr][ckw] = rkh1;                                   \
    *(short8v*)&Khl[1][0][kr][ckw] = rkl0;                                   \
    *(short8v*)&Khl[1][1][kr][ckw] = rkl1;                                   \
    *(short8v*)&Vtl[kr][kc * 8]      = rv0;                                  \
    *(short8v*)&Vtl[kr][kc * 8 + 32] = rv1; }

// S^T block n: rows k = n*16+lh*4+j, col q = l4. 4 LDS reads + 6 MFMA.
#define QKSTEP(sN, n) {                                                      \
    const short8v kh0 = *(const short8v*)&Khl[0][0][(n)*16 + l4][csr];       \
    const short8v kh1 = *(const short8v*)&Khl[0][1][(n)*16 + l4][csr];       \
    const short8v kl0 = *(const short8v*)&Khl[1][0][(n)*16 + l4][csr];       \
    const short8v kl1 = *(const short8v*)&Khl[1][1][(n)*16 + l4][csr];       \
    sN = __builtin_amdgcn_mfma_f32_16x16x32_bf16(kh0, aqh0, sN, 0, 0, 0);    \
    sN = __builtin_amdgcn_mfma_f32_16x16x32_bf16(kh0, aql0, sN, 0, 0, 0);    \
    sN = __builtin_amdgcn_mfma_f32_16x16x32_bf16(kl0, aqh0, sN, 0, 0, 0);    \
    sN = __builtin_amdgcn_mfma_f32_16x16x32_bf16(kh1, aqh1, sN, 0, 0, 0);    \
    sN = __builtin_amdgcn_mfma_f32_16x16x32_bf16(kh1, aql1, sN, 0, 0, 0);    \
    sN = __builtin_amdgcn_mfma_f32_16x16x32_bf16(kl1, aqh1, sN, 0, 0, 0); }

#define MASKN(sN, n) {                                                       \
    const int kb0 = kb + (n)*16 + lh*4;                                      \
    if (kb0 + 0 > qrow) sN[0] = -1e30f;                                      \
    if (kb0 + 1 > qrow) sN[1] = -1e30f;                                      \
    if (kb0 + 2 > qrow) sN[2] = -1e30f;                                      \
    if (kb0 + 3 > qrow) sN[3] = -1e30f; }

#define EXPN(sN) {                                                           \
    sN[0] = __expf(sN[0] - nm); sN[1] = __expf(sN[1] - nm);                  \
    sN[2] = __expf(sN[2] - nm); sN[3] = __expf(sN[3] - nm); }

#define PWRITE(sN, n) {                                                      \
    unsigned pa, pb;                                                         \
    asm("v_cvt_pk_bf16_f32 %0, %1, %2" : "=v"(pa) : "v"(sN[0]), "v"(sN[1]));\
    asm("v_cvt_pk_bf16_f32 %0, %1, %2" : "=v"(pb) : "v"(sN[2]), "v"(sN[3]));\
    *(unsigned*)&Pl[wv][l4][(n)*16 + lh*4]     = pa;                         \
    *(unsigned*)&Pl[wv][l4][(n)*16 + lh*4 + 2] = pb; }

#define PVSTEP(kb2) {                                                        \
    const short8v ap  = *(const short8v*)&Pl[wv][l4][(kb2)*32 + lh*8];       \
    const short8v bv0 = *(const short8v*)&Vtl[ 0 + l4][(kb2)*32 + lh*8];     \
    const short8v bv1 = *(const short8v*)&Vtl[16 + l4][(kb2)*32 + lh*8];     \
    const short8v bv2 = *(const short8v*)&Vtl[32 + l4][(kb2)*32 + lh*8];     \
    const short8v bv3 = *(const short8v*)&Vtl[48 + l4][(kb2)*32 + lh*8];     \
    o0 = __builtin_amdgcn_mfma_f32_16x16x32_bf16(bv0, ap, o0, 0, 0, 0);      \
    o1 = __builtin_amdgcn_mfma_f32_16x16x32_bf16(bv1, ap, o1, 0, 0, 0);      \
    o2 = __builtin_amdgcn_mfma_f32_16x16x32_bf16(bv2, ap, o2, 0, 0, 0);      \
    o3 = __builtin_amdgcn_mfma_f32_16x16x32_bf16(bv3, ap, o3, 0, 0, 0); }

  LOADR(0); WRITES();
  __syncthreads();

  for (int kt = 0; kt < nt; kt++) {
    const bool pf = (kt + 1 < nt);
    if (pf) LOADR(kt + 1);          // issue next-tile loads early (overlap)

    // ---- S^T = K Q^T (split bf16)
    f32x4 s0 = {0,0,0,0}, s1 = {0,0,0,0}, s2 = {0,0,0,0}, s3 = {0,0,0,0};
    QKSTEP(s0, 0) QKSTEP(s1, 1) QKSTEP(s2, 2) QKSTEP(s3, 3)

    // ---- causal mask + lane-local online softmax (lane = q row)
    const int kb = kt * 64;
    MASKN(s0, 0) MASKN(s1, 1) MASKN(s2, 2) MASKN(s3, 3)

    float vmax = fmaxf(fmaxf(fmaxf(s0[0], s0[1]), fmaxf(s0[2], s0[3])),
                       fmaxf(fmaxf(s1[0], s1[1]), fmaxf(s1[2], s1[3])));
    vmax = fmaxf(vmax, fmaxf(fmaxf(s2[0], s2[1]), fmaxf(s2[2], s2[3])));
    vmax = fmaxf(vmax, fmaxf(fmaxf(s3[0], s3[1]), fmaxf(s3[2], s3[3])));
    vmax = fmaxf(vmax, __shfl_xor(vmax, 16));
    vmax = fmaxf(vmax, __shfl_xor(vmax, 32));

    const float nm = fmaxf(mrun, vmax);
    const float corr = __expf(mrun - nm);
    mrun = nm;

    EXPN(s0) EXPN(s1) EXPN(s2) EXPN(s3)

    float rs = (s0[0] + s0[1]) + (s0[2] + s0[3]) + (s1[0] + s1[1]) + (s1[2] + s1[3])
             + (s2[0] + s2[1]) + (s2[2] + s2[3]) + (s3[0] + s3[1]) + (s3[2] + s3[3]);
    rs += __shfl_xor(rs, 16);
    rs += __shfl_xor(rs, 32);
    lsum = lsum * corr + rs;

    o0 *= corr; o1 *= corr; o2 *= corr; o3 *= corr;

    // ---- P -> LDS (packed b32 writes; same-wave in-order LDS, no barrier)
    PWRITE(s0, 0) PWRITE(s1, 1) PWRITE(s2, 2) PWRITE(s3, 3)

    // ---- O^T += V^T P^T
    PVSTEP(0) PVSTEP(1)

    // ---- publish next tile (single buffer: write after all waves read)
    if (pf) {
      __syncthreads();
      WRITES();
      __syncthreads();
    }
  }

  // ---- epilogue: normalize + hi/lo bf16 split; O^T: lane l4 = q, rows = d
  const float inv = 1.0f / lsum;
  const size_t rowoff = ((size_t)(bI * SEQ + qrow)) * DM + h * DH;
  #pragma unroll
  for (int df = 0; df < 4; df++) {
    const f32x4 ov = (df == 0) ? o0 : (df == 1) ? o1 : (df == 2) ? o2 : o3;
    #pragma unroll
    for (int jp = 0; jp < 2; jp++) {
      const float x0 = ov[2 * jp] * inv;
      const float x1 = ov[2 * jp + 1] * inv;
      const unsigned short h0 = f2bf(x0), h1 = f2bf(x1);
      const unsigned short g0 = f2bf(x0 - bf2f(h0)), g1 = f2bf(x1 - bf2f(h1));
      const size_t col = rowoff + df * 16 + lh * 4 + 2 * jp;
      *(unsigned*)&AAh[col] = (unsigned)h0 | ((unsigned)h1 << 16);
      *(unsigned*)&AAl[col] = (unsigned)g0 | ((unsigned)g1 << 16);
    }
  }
#undef LOADR
#undef WRITES
#undef QKSTEP
#undef MASKN
#undef EXPN
#undef PWRITE
#undef PVSTEP
}

// ---------------------------------------------------------------------------
// ws layout (56 MB):
//   0MB: Xh(8) Xl(8)      -> after QKV consumed: AAh(8) AAl(8) from attn
//  16MB: Kh(8) Kl(8)
//  32MB: Vt(8)
//  40MB: WT 4x(hi 2MB + lo 2MB) = 16
// d_out: Qh(8) Ql(8) scratch, then final fp32 out (16).
// ---------------------------------------------------------------------------
extern "C" void kernel_launch(void* const* d_in, const int* in_sizes, int n_in,
                              void* d_out, int out_size, void* d_ws, size_t ws_size,
                              hipStream_t stream) {
  const float* x  = (const float*)d_in[0];
  const float* qw = (const float*)d_in[1];
  const float* kw = (const float*)d_in[2];
  const float* vw = (const float*)d_in[3];
  const float* ow = (const float*)d_in[4];

  char* ws = (char*)d_ws;
  ushort_t* Xh  = (ushort_t*)ws;
  ushort_t* Xl  = Xh + 4194304;
  ushort_t* AAh = Xh;                      // Xh/Xl dead after QKV gemm
  ushort_t* AAl = Xl;
  ushort_t* Kh  = (ushort_t*)(ws + (16u << 20));
  ushort_t* Kl  = Kh + 4194304;
  ushort_t* Vt  = (ushort_t*)(ws + (32u << 20));
  ushort_t* WT  = (ushort_t*)(ws + (40u << 20));
  ushort_t* Qh  = (ushort_t*)d_out;
  ushort_t* Ql  = Qh + 4194304;
  float*    out = (float*)d_out;

  dim3 blk(256);
  split_f32<<<dim3(2048), blk, 0, stream>>>(x, Xh, Xl, 524288);
  wtrans<<<dim3(16, 16, 4), blk, 0, stream>>>(qw, kw, vw, ow, WT);
  mfma_gemm<<<dim3(8, 32, 3), blk, 0, stream>>>(
      Xh, Xl, WT, 0, Qh, Ql, Kh, Kl, Vt, nullptr);
  attn_mfma<<<dim3(SEQ / 64, BATCH * NH), blk, 0, stream>>>(
      Qh, Ql, Kh, Kl, Vt, AAh, AAl);
  mfma_gemm<<<dim3(8, 32, 1), blk, 0, stream>>>(
      AAh, AAl, WT, 3, nullptr, nullptr, nullptr, nullptr, nullptr, out);
}

// Round 8
// 217.935 us; speedup vs baseline: 1.4008x; 1.1258x over previous
//
#include <hip/hip_runtime.h>
#include <hip/hip_bf16.h>
#include <math.h>

#define SEQ    2048
#define BATCH  2
#define DM     1024
#define NH     16
#define DH     64
#define BS_ROWS 4096
#define KDIM   1024

typedef __attribute__((ext_vector_type(8))) short short8v;
typedef __attribute__((ext_vector_type(4))) float f32x4;
typedef unsigned short ushort_t;

__device__ __forceinline__ unsigned short f2bf(float f) {
  union { float f; unsigned u; } v; v.f = f;
  unsigned r = (v.u + 0x7FFF + ((v.u >> 16) & 1)) >> 16;
  return (unsigned short)r;
}
__device__ __forceinline__ float bf2f(unsigned short h) {
  union { unsigned u; float f; } v; v.u = ((unsigned)h) << 16;
  return v.f;
}

// async global->LDS, 16B per lane; lds ptr must be wave-uniform base (+lane*16 implied)
__device__ __forceinline__ void gl16(const void* g, void* l) {
  __builtin_amdgcn_global_load_lds(
      (const __attribute__((address_space(1))) unsigned int*)g,
      (__attribute__((address_space(3))) unsigned int*)l,
      16, 0, 0);
}

// ---------------------------------------------------------------------------
// fp32 -> hi/lo bf16 split (8 elems/thread)
// ---------------------------------------------------------------------------
__global__ __launch_bounds__(256)
void split_f32(const float* __restrict__ src, ushort_t* __restrict__ h,
               ushort_t* __restrict__ l, int n8)
{
  const int i = blockIdx.x * 256 + threadIdx.x;
  if (i >= n8) return;
  const float4 v0 = ((const float4*)src)[2 * i];
  const float4 v1 = ((const float4*)src)[2 * i + 1];
  const float vals[8] = {v0.x, v0.y, v0.z, v0.w, v1.x, v1.y, v1.z, v1.w};
  short8v hv, lv;
  #pragma unroll
  for (int e = 0; e < 8; e++) {
    const unsigned short hb = f2bf(vals[e]);
    hv[e] = (short)hb;
    lv[e] = (short)f2bf(vals[e] - bf2f(hb));
  }
  ((short8v*)h)[i] = hv;
  ((short8v*)l)[i] = lv;
}

// ---------------------------------------------------------------------------
// weight transpose + split. z<=1 (qw,kw): hi+lo. z>=2 (vw,ow): hi only
// (lo never consumed — V drops Xh*Wl, out-proj is plain bf16).
// ---------------------------------------------------------------------------
__global__ __launch_bounds__(256)
void wtrans(const float* __restrict__ w0, const float* __restrict__ w1,
            const float* __restrict__ w2, const float* __restrict__ w3,
            ushort_t* __restrict__ WT)
{
  __shared__ float tile[64][65];
  const int z = blockIdx.z;
  const float* __restrict__ W = (z == 0) ? w0 : (z == 1) ? w1 : (z == 2) ? w2 : w3;
  ushort_t* __restrict__ Oh = WT + (size_t)z * 2097152;
  ushort_t* __restrict__ Ol = Oh + 1048576;

  const int n0 = blockIdx.x * 64, k0 = blockIdx.y * 64;
  const int r  = threadIdx.x >> 2;
  const int c0 = (threadIdx.x & 3) * 16;

  #pragma unroll
  for (int i = 0; i < 4; i++) {
    const float4 v = *(const float4*)&W[(size_t)(k0 + r) * KDIM + n0 + c0 + 4 * i];
    tile[r][c0 + 4 * i + 0] = v.x; tile[r][c0 + 4 * i + 1] = v.y;
    tile[r][c0 + 4 * i + 2] = v.z; tile[r][c0 + 4 * i + 3] = v.w;
  }
  __syncthreads();

  #pragma unroll
  for (int c = 0; c < 2; c++) {
    short8v hv, lv;
    #pragma unroll
    for (int e = 0; e < 8; e++) {
      const float x = tile[c0 + c * 8 + e][r];
      const unsigned short hb = f2bf(x);
      hv[e] = (short)hb;
      lv[e] = (short)f2bf(x - bf2f(hb));
    }
    const size_t off = (size_t)(n0 + r) * KDIM + k0 + c0 + c * 8;
    *(short8v*)&Oh[off] = hv;
    if (z <= 1) *(short8v*)&Ol[off] = lv;
  }
}

// ---------------------------------------------------------------------------
// Split-bf16 MFMA GEMM with per-mode precision:
//   mode 0/1 (Q,K): hh + h*l + l*h (3 MFMA units)  -> RoPE+split epilogue
//   mode 2   (V)  : hh + l*h       (2)             -> Vt bf16 transposed
//   mode 3   (out): hh             (1)             -> fp32 C
// ---------------------------------------------------------------------------
#define M1(a_, b_, c_) c_ = __builtin_amdgcn_mfma_f32_16x16x32_bf16(a_, b_, c_, 0, 0, 0);

#define M16(p_, q_)                                                          \
  M1(p_##0, q_##0, c00) M1(p_##0, q_##1, c01) M1(p_##0, q_##2, c02) M1(p_##0, q_##3, c03) \
  M1(p_##1, q_##0, c10) M1(p_##1, q_##1, c11) M1(p_##1, q_##2, c12) M1(p_##1, q_##3, c13) \
  M1(p_##2, q_##0, c20) M1(p_##2, q_##1, c21) M1(p_##2, q_##2, c22) M1(p_##2, q_##3, c23) \
  M1(p_##3, q_##0, c30) M1(p_##3, q_##1, c31) M1(p_##3, q_##2, c32) M1(p_##3, q_##3, c33)

__global__ __launch_bounds__(256, 2)
void mfma_gemm(const ushort_t* __restrict__ Ah, const ushort_t* __restrict__ Al,
               const ushort_t* __restrict__ WT, int zbase,
               ushort_t* __restrict__ Qh, ushort_t* __restrict__ Ql,
               ushort_t* __restrict__ Kh, ushort_t* __restrict__ Kl,
               ushort_t* __restrict__ Vt, float* __restrict__ Cf)
{
  const int mode = zbase + blockIdx.z;
  const bool needBl = (mode <= 1);   // A_h * B_l term
  const bool needAl = (mode <= 2);   // A_l * B_h term
  const ushort_t* __restrict__ Bh = WT + (size_t)mode * 2097152;
  const ushort_t* __restrict__ Bl = Bh + 1048576;

  __shared__ ushort_t Ash[128][32];
  __shared__ ushort_t Asl[128][32];
  __shared__ ushort_t Bsh[128][32];
  __shared__ ushort_t Bsl[128][32];

  const int t = threadIdx.x;
  const int lane = t & 63, w = t >> 6;
  const int l4 = lane & 15, lh = lane >> 4;
  const int wm = w >> 1, wn = w & 1;
  const int row0 = blockIdx.y * 128, col0 = blockIdx.x * 128;

  const int srow = t >> 2;
  const int scol = (t & 3) * 8;

  f32x4 c00 = {0,0,0,0}, c01 = {0,0,0,0}, c02 = {0,0,0,0}, c03 = {0,0,0,0};
  f32x4 c10 = {0,0,0,0}, c11 = {0,0,0,0}, c12 = {0,0,0,0}, c13 = {0,0,0,0};
  f32x4 c20 = {0,0,0,0}, c21 = {0,0,0,0}, c22 = {0,0,0,0}, c23 = {0,0,0,0};
  f32x4 c30 = {0,0,0,0}, c31 = {0,0,0,0}, c32 = {0,0,0,0}, c33 = {0,0,0,0};

  const int rA = wm * 64 + l4;
  const int rB = wn * 64 + l4;
  const int cF = lh * 8;

  for (int k0 = 0; k0 < KDIM; k0 += 32) {
    #pragma unroll
    for (int r = 0; r < 2; r++) {
      const int row = srow + r * 64;
      const size_t gA = (size_t)(row0 + row) * KDIM + k0 + scol;
      const size_t gB = (size_t)(col0 + row) * KDIM + k0 + scol;
      const int lo = w * 1024 + r * 4096;
      gl16(Ah + gA, (char*)Ash + lo);
      gl16(Bh + gB, (char*)Bsh + lo);
      if (needAl) gl16(Al + gA, (char*)Asl + lo);
      if (needBl) gl16(Bl + gB, (char*)Bsl + lo);
    }
    __syncthreads();

    const short8v ah0 = *(const short8v*)&Ash[rA +  0][cF];
    const short8v ah1 = *(const short8v*)&Ash[rA + 16][cF];
    const short8v ah2 = *(const short8v*)&Ash[rA + 32][cF];
    const short8v ah3 = *(const short8v*)&Ash[rA + 48][cF];
    const short8v bh0 = *(const short8v*)&Bsh[rB +  0][cF];
    const short8v bh1 = *(const short8v*)&Bsh[rB + 16][cF];
    const short8v bh2 = *(const short8v*)&Bsh[rB + 32][cF];
    const short8v bh3 = *(const short8v*)&Bsh[rB + 48][cF];

    M16(ah, bh)

    if (needBl) {
      const short8v bl0 = *(const short8v*)&Bsl[rB +  0][cF];
      const short8v bl1 = *(const short8v*)&Bsl[rB + 16][cF];
      const short8v bl2 = *(const short8v*)&Bsl[rB + 32][cF];
      const short8v bl3 = *(const short8v*)&Bsl[rB + 48][cF];
      M16(ah, bl)
    }
    if (needAl) {
      const short8v al0 = *(const short8v*)&Asl[rA +  0][cF];
      const short8v al1 = *(const short8v*)&Asl[rA + 16][cF];
      const short8v al2 = *(const short8v*)&Asl[rA + 32][cF];
      const short8v al3 = *(const short8v*)&Asl[rA + 48][cF];
      M16(al, bh)
    }
    __syncthreads();
  }

  f32x4 acc[4][4];
  acc[0][0]=c00; acc[0][1]=c01; acc[0][2]=c02; acc[0][3]=c03;
  acc[1][0]=c10; acc[1][1]=c11; acc[1][2]=c12; acc[1][3]=c13;
  acc[2][0]=c20; acc[2][1]=c21; acc[2][2]=c22; acc[2][3]=c23;
  acc[3][0]=c30; acc[3][1]=c31; acc[3][2]=c32; acc[3][3]=c33;

  if (mode <= 1) {
    const float scale = (mode == 0) ? 0.03125f : 1.0f;
    ushort_t* __restrict__ Hp = (mode == 0) ? Qh : Kh;
    ushort_t* __restrict__ Lp = (mode == 0) ? Ql : Kl;
    #pragma unroll
    for (int mf = 0; mf < 4; mf++)
      #pragma unroll
      for (int nf = 0; nf < 4; nf++) {
        const int col = col0 + wn * 64 + nf * 16 + l4;
        const int p = (col & (DH - 1)) >> 1;
        const float fr = exp2f((float)p * -0.41524101186092030f);
        const float sgn = (col & 1) ? 1.0f : -1.0f;
        #pragma unroll
        for (int j = 0; j < 4; j++) {
          const int grow = row0 + wm * 64 + mf * 16 + lh * 4 + j;
          const float s = (float)(grow & (SEQ - 1));
          float sn, cs;
          sincosf(s * fr, &sn, &cs);
          const float val = acc[mf][nf][j];
          const float par = __shfl_xor(val, 1);
          const float out = val * cs + par * (sgn * sn);
          const float xsc = out * scale;
          const unsigned short hb = f2bf(xsc);
          Hp[(size_t)grow * DM + col] = hb;
          Lp[(size_t)grow * DM + col] = f2bf(xsc - bf2f(hb));
        }
      }
  } else if (mode == 2) {
    #pragma unroll
    for (int mf = 0; mf < 4; mf++)
      #pragma unroll
      for (int nf = 0; nf < 4; nf++) {
        const int col = col0 + wn * 64 + nf * 16 + l4;
        const int hh = col >> 6, dd = col & (DH - 1);
        #pragma unroll
        for (int j = 0; j < 4; j++) {
          const int grow = row0 + wm * 64 + mf * 16 + lh * 4 + j;
          const int b = grow >> 11, ss = grow & (SEQ - 1);
          Vt[((size_t)((b * NH + hh) * DH + dd)) * SEQ + ss] = f2bf(acc[mf][nf][j]);
        }
      }
  } else {
    #pragma unroll
    for (int mf = 0; mf < 4; mf++)
      #pragma unroll
      for (int nf = 0; nf < 4; nf++) {
        const int col = col0 + wn * 64 + nf * 16 + l4;
        #pragma unroll
        for (int j = 0; j < 4; j++) {
          const int grow = row0 + wm * 64 + mf * 16 + lh * 4 + j;
          Cf[(size_t)grow * DM + col] = acc[mf][nf][j];
        }
      }
  }
}

// ---------------------------------------------------------------------------
// MFMA flash attention (round-7 structure, verified). Epilogue now writes
// only AAh (bf16) — out-proj is plain bf16.
// ---------------------------------------------------------------------------
__global__ __launch_bounds__(256, 4)
void attn_mfma(const ushort_t* __restrict__ Qh, const ushort_t* __restrict__ Ql,
               const ushort_t* __restrict__ Kh, const ushort_t* __restrict__ Kl,
               const ushort_t* __restrict__ Vt, ushort_t* __restrict__ AAh)
{
  __shared__ __align__(16) ushort_t Khl[2][2][64][32]; // [hi/lo][db][row][d] 16KB
  __shared__ __align__(16) ushort_t Vtl[64][72];       // [d][k]             9.2KB
  __shared__ __align__(16) ushort_t Pl[4][16][72];     // [wave][q][k]       9.2KB

  const int t = threadIdx.x;
  const int lane = t & 63, wv = t >> 6;
  const int l4 = lane & 15, lh = lane >> 4;
  const int qblk = blockIdx.x, bh = blockIdx.y;
  const int bI = bh >> 4, h = bh & 15;
  const int q0w = qblk * 64 + wv * 16;
  const int qrow = q0w + l4;

  const int kr = t >> 2, kc = t & 3;
  const int ckw = (kc ^ ((kr >> 1) & 3)) * 8;
  const int csr = (lh ^ ((l4 >> 1) & 3)) * 8;

  short8v aqh0, aqh1, aql0, aql1;
  {
    const size_t qoff = (size_t)((bI * SEQ) + qrow) * DM + h * DH;
    aqh0 = *(const short8v*)&Qh[qoff + lh * 8];
    aqh1 = *(const short8v*)&Qh[qoff + 32 + lh * 8];
    aql0 = *(const short8v*)&Ql[qoff + lh * 8];
    aql1 = *(const short8v*)&Ql[qoff + 32 + lh * 8];
  }

  f32x4 o0 = {0,0,0,0}, o1 = {0,0,0,0}, o2 = {0,0,0,0}, o3 = {0,0,0,0};
  float mrun = -1e30f, lsum = 0.f;

  const ushort_t* __restrict__ Vg = Vt + (size_t)bh * DH * SEQ;
  const size_t kgbase = (size_t)(bI * SEQ + kr) * DM + h * DH + kc * 8;
  const int nt = qblk + 1;

  short8v rkh0, rkh1, rkl0, rkl1, rv0, rv1;

#define LOADR(kt_) {                                                         \
    const size_t ko = kgbase + (size_t)(kt_) * 64 * DM;                      \
    rkh0 = *(const short8v*)&Kh[ko];                                         \
    rkh1 = *(const short8v*)&Kh[ko + 32];                                    \
    rkl0 = *(const short8v*)&Kl[ko];                                         \
    rkl1 = *(const short8v*)&Kl[ko + 32];                                    \
    const size_t vo = (size_t)kr * SEQ + (kt_) * 64 + kc * 8;                \
    rv0 = *(const short8v*)&Vg[vo];                                          \
    rv1 = *(const short8v*)&Vg[vo + 32]; }

#define WRITES() {                                                           \
    *(short8v*)&Khl[0][0][kr][ckw] = rkh0;                                   \
    *(short8v*)&Khl[0][1][kr][ckw] = rkh1;                                   \
    *(short8v*)&Khl[1][0][kr][ckw] = rkl0;                                   \
    *(short8v*)&Khl[1][1][kr][ckw] = rkl1;                                   \
    *(short8v*)&Vtl[kr][kc * 8]      = rv0;                                  \
    *(short8v*)&Vtl[kr][kc * 8 + 32] = rv1; }

#define QKSTEP(sN, n) {                                                      \
    const short8v kh0 = *(const short8v*)&Khl[0][0][(n)*16 + l4][csr];       \
    const short8v kh1 = *(const short8v*)&Khl[0][1][(n)*16 + l4][csr];       \
    const short8v kl0 = *(const short8v*)&Khl[1][0][(n)*16 + l4][csr];       \
    const short8v kl1 = *(const short8v*)&Khl[1][1][(n)*16 + l4][csr];       \
    sN = __builtin_amdgcn_mfma_f32_16x16x32_bf16(kh0, aqh0, sN, 0, 0, 0);    \
    sN = __builtin_amdgcn_mfma_f32_16x16x32_bf16(kh0, aql0, sN, 0, 0, 0);    \
    sN = __builtin_amdgcn_mfma_f32_16x16x32_bf16(kl0, aqh0, sN, 0, 0, 0);    \
    sN = __builtin_amdgcn_mfma_f32_16x16x32_bf16(kh1, aqh1, sN, 0, 0, 0);    \
    sN = __builtin_amdgcn_mfma_f32_16x16x32_bf16(kh1, aql1, sN, 0, 0, 0);    \
    sN = __builtin_amdgcn_mfma_f32_16x16x32_bf16(kl1, aqh1, sN, 0, 0, 0); }

#define MASKN(sN, n) {                                                       \
    const int kb0 = kb + (n)*16 + lh*4;                                      \
    if (kb0 + 0 > qrow) sN[0] = -1e30f;                                      \
    if (kb0 + 1 > qrow) sN[1] = -1e30f;                                      \
    if (kb0 + 2 > qrow) sN[2] = -1e30f;                                      \
    if (kb0 + 3 > qrow) sN[3] = -1e30f; }

#define EXPN(sN) {                                                           \
    sN[0] = __expf(sN[0] - nm); sN[1] = __expf(sN[1] - nm);                  \
    sN[2] = __expf(sN[2] - nm); sN[3] = __expf(sN[3] - nm); }

#define PWRITE(sN, n) {                                                      \
    unsigned pa, pb;                                                         \
    asm("v_cvt_pk_bf16_f32 %0, %1, %2" : "=v"(pa) : "v"(sN[0]), "v"(sN[1]));\
    asm("v_cvt_pk_bf16_f32 %0, %1, %2" : "=v"(pb) : "v"(sN[2]), "v"(sN[3]));\
    *(unsigned*)&Pl[wv][l4][(n)*16 + lh*4]     = pa;                         \
    *(unsigned*)&Pl[wv][l4][(n)*16 + lh*4 + 2] = pb; }

#define PVSTEP(kb2) {                                                        \
    const short8v ap  = *(const short8v*)&Pl[wv][l4][(kb2)*32 + lh*8];       \
    const short8v bv0 = *(const short8v*)&Vtl[ 0 + l4][(kb2)*32 + lh*8];     \
    const short8v bv1 = *(const short8v*)&Vtl[16 + l4][(kb2)*32 + lh*8];     \
    const short8v bv2 = *(const short8v*)&Vtl[32 + l4][(kb2)*32 + lh*8];     \
    const short8v bv3 = *(const short8v*)&Vtl[48 + l4][(kb2)*32 + lh*8];     \
    o0 = __builtin_amdgcn_mfma_f32_16x16x32_bf16(bv0, ap, o0, 0, 0, 0);      \
    o1 = __builtin_amdgcn_mfma_f32_16x16x32_bf16(bv1, ap, o1, 0, 0, 0);      \
    o2 = __builtin_amdgcn_mfma_f32_16x16x32_bf16(bv2, ap, o2, 0, 0, 0);      \
    o3 = __builtin_amdgcn_mfma_f32_16x16x32_bf16(bv3, ap, o3, 0, 0, 0); }

  LOADR(0); WRITES();
  __syncthreads();

  for (int kt = 0; kt < nt; kt++) {
    const bool pf = (kt + 1 < nt);
    if (pf) LOADR(kt + 1);

    f32x4 s0 = {0,0,0,0}, s1 = {0,0,0,0}, s2 = {0,0,0,0}, s3 = {0,0,0,0};
    QKSTEP(s0, 0) QKSTEP(s1, 1) QKSTEP(s2, 2) QKSTEP(s3, 3)

    const int kb = kt * 64;
    MASKN(s0, 0) MASKN(s1, 1) MASKN(s2, 2) MASKN(s3, 3)

    float vmax = fmaxf(fmaxf(fmaxf(s0[0], s0[1]), fmaxf(s0[2], s0[3])),
                       fmaxf(fmaxf(s1[0], s1[1]), fmaxf(s1[2], s1[3])));
    vmax = fmaxf(vmax, fmaxf(fmaxf(s2[0], s2[1]), fmaxf(s2[2], s2[3])));
    vmax = fmaxf(vmax, fmaxf(fmaxf(s3[0], s3[1]), fmaxf(s3[2], s3[3])));
    vmax = fmaxf(vmax, __shfl_xor(vmax, 16));
    vmax = fmaxf(vmax, __shfl_xor(vmax, 32));

    const float nm = fmaxf(mrun, vmax);
    const float corr = __expf(mrun - nm);
    mrun = nm;

    EXPN(s0) EXPN(s1) EXPN(s2) EXPN(s3)

    float rs = (s0[0] + s0[1]) + (s0[2] + s0[3]) + (s1[0] + s1[1]) + (s1[2] + s1[3])
             + (s2[0] + s2[1]) + (s2[2] + s2[3]) + (s3[0] + s3[1]) + (s3[2] + s3[3]);
    rs += __shfl_xor(rs, 16);
    rs += __shfl_xor(rs, 32);
    lsum = lsum * corr + rs;

    o0 *= corr; o1 *= corr; o2 *= corr; o3 *= corr;

    PWRITE(s0, 0) PWRITE(s1, 1) PWRITE(s2, 2) PWRITE(s3, 3)

    PVSTEP(0) PVSTEP(1)

    if (pf) {
      __syncthreads();
      WRITES();
      __syncthreads();
    }
  }

  // ---- epilogue: normalize + bf16 (hi only; out-proj is plain bf16)
  const float inv = 1.0f / lsum;
  const size_t rowoff = ((size_t)(bI * SEQ + qrow)) * DM + h * DH;
  #pragma unroll
  for (int df = 0; df < 4; df++) {
    const f32x4 ov = (df == 0) ? o0 : (df == 1) ? o1 : (df == 2) ? o2 : o3;
    #pragma unroll
    for (int jp = 0; jp < 2; jp++) {
      const float x0 = ov[2 * jp] * inv;
      const float x1 = ov[2 * jp + 1] * inv;
      const unsigned short h0 = f2bf(x0), h1 = f2bf(x1);
      const size_t col = rowoff + df * 16 + lh * 4 + 2 * jp;
      *(unsigned*)&AAh[col] = (unsigned)h0 | ((unsigned)h1 << 16);
    }
  }
#undef LOADR
#undef WRITES
#undef QKSTEP
#undef MASKN
#undef EXPN
#undef PWRITE
#undef PVSTEP
}

// ---------------------------------------------------------------------------
// ws layout (56 MB):
//   0MB: Xh(8) Xl(8)      -> after QKV consumed: AAh(8) from attn
//  16MB: Kh(8) Kl(8)
//  32MB: Vt(8)
//  40MB: WT 4x(hi 2MB + lo 2MB) = 16
// d_out: Qh(8) Ql(8) scratch, then final fp32 out (16).
// ---------------------------------------------------------------------------
extern "C" void kernel_launch(void* const* d_in, const int* in_sizes, int n_in,
                              void* d_out, int out_size, void* d_ws, size_t ws_size,
                              hipStream_t stream) {
  const float* x  = (const float*)d_in[0];
  const float* qw = (const float*)d_in[1];
  const float* kw = (const float*)d_in[2];
  const float* vw = (const float*)d_in[3];
  const float* ow = (const float*)d_in[4];

  char* ws = (char*)d_ws;
  ushort_t* Xh  = (ushort_t*)ws;
  ushort_t* Xl  = Xh + 4194304;
  ushort_t* AAh = Xh;                      // Xh dead after QKV gemm
  ushort_t* Kh  = (ushort_t*)(ws + (16u << 20));
  ushort_t* Kl  = Kh + 4194304;
  ushort_t* Vt  = (ushort_t*)(ws + (32u << 20));
  ushort_t* WT  = (ushort_t*)(ws + (40u << 20));
  ushort_t* Qh  = (ushort_t*)d_out;
  ushort_t* Ql  = Qh + 4194304;
  float*    out = (float*)d_out;

  dim3 blk(256);
  split_f32<<<dim3(2048), blk, 0, stream>>>(x, Xh, Xl, 524288);
  wtrans<<<dim3(16, 16, 4), blk, 0, stream>>>(qw, kw, vw, ow, WT);
  mfma_gemm<<<dim3(8, 32, 3), blk, 0, stream>>>(
      Xh, Xl, WT, 0, Qh, Ql, Kh, Kl, Vt, nullptr);
  attn_mfma<<<dim3(SEQ / 64, BATCH * NH), blk, 0, stream>>>(
      Qh, Ql, Kh, Kl, Vt, AAh);
  mfma_gemm<<<dim3(8, 32, 1), blk, 0, stream>>>(
      AAh, nullptr, WT, 3, nullptr, nullptr, nullptr, nullptr, nullptr, out);
}